// Round 1
// baseline (706.447 us; speedup 1.0000x reference)
//
#include <hip/hip_runtime.h>

#define S_LEN 2048
#define NH 16
#define DH 64
#define DM 1024
#define NB 2
#define BS 4096  // NB*S_LEN

typedef __attribute__((ext_vector_type(4))) float f32x4;
typedef __attribute__((ext_vector_type(8))) short bfrag;  // 8 bf16 in 4 VGPRs

__device__ __forceinline__ unsigned short f2bf(float f) {
    unsigned u = __builtin_bit_cast(unsigned, f);
    u += 0x7FFFu + ((u >> 16) & 1u);
    return (unsigned short)(u >> 16);
}

// ---------------- fp32 -> bf16 cast ----------------
__global__ __launch_bounds__(256) void cast_kernel(const float* __restrict__ in,
                                                   unsigned short* __restrict__ out, int n4) {
    int i = blockIdx.x * 256 + threadIdx.x;
    if (i < n4) {
        float4 v = reinterpret_cast<const float4*>(in)[i];
        ushort4 o;
        o.x = f2bf(v.x); o.y = f2bf(v.y); o.z = f2bf(v.z); o.w = f2bf(v.w);
        reinterpret_cast<ushort4*>(out)[i] = o;
    }
}

// ---------------- generic B^T GEMM: C[m,n] = sum_k A[m,k]*Bt[n,k] ----------------
// A: bf16 [M][K], Bt: bf16 [N][K]. 128x128 tile, BK=64, 4 waves (2x2), wave=64x64.
// EPI 0: write bf16 to (b,h,s,d)   [projection Q,K]
// EPI 1: write bf16 to (b,h,d,s)   [projection V, transposed for PV]
// EPI 2: write fp32 [M][N]         [output projection]
template <int EPI>
__global__ __launch_bounds__(256) void gemm_bt(const unsigned short* __restrict__ A,
                                               const unsigned short* __restrict__ Bt,
                                               void* __restrict__ Out, int M, int N, int K) {
    const int tid = threadIdx.x;
    const int lane = tid & 63;
    const int w = tid >> 6, wr = w >> 1, wc = w & 1;
    const int m0 = blockIdx.y * 128;
    const int n0 = blockIdx.x * 128;

    __shared__ unsigned short sA[128 * 64];
    __shared__ unsigned short sB[128 * 64];

    f32x4 acc[4][4];
#pragma unroll
    for (int i = 0; i < 4; ++i)
#pragma unroll
        for (int j = 0; j < 4; ++j) acc[i][j] = (f32x4){0.f, 0.f, 0.f, 0.f};

    for (int k0 = 0; k0 < K; k0 += 64) {
#pragma unroll
        for (int i = 0; i < 4; ++i) {
            int c = i * 256 + tid;      // 1024 chunks of 8 bf16 per tile
            int row = c >> 3, col8 = c & 7;
            int swz = (col8 * 8) ^ ((row & 7) * 8);
            *reinterpret_cast<int4*>(sA + row * 64 + swz) =
                *reinterpret_cast<const int4*>(A + (size_t)(m0 + row) * K + k0 + col8 * 8);
            *reinterpret_cast<int4*>(sB + row * 64 + swz) =
                *reinterpret_cast<const int4*>(Bt + (size_t)(n0 + row) * K + k0 + col8 * 8);
        }
        __syncthreads();
#pragma unroll
        for (int kk = 0; kk < 2; ++kk) {
            bfrag a[4], b[4];
#pragma unroll
            for (int f = 0; f < 4; ++f) {
                int ra = wr * 64 + f * 16 + (lane & 15);
                a[f] = *reinterpret_cast<const bfrag*>(
                    sA + ra * 64 + ((kk * 32 + (lane >> 4) * 8) ^ ((ra & 7) * 8)));
                int rb = wc * 64 + f * 16 + (lane & 15);
                b[f] = *reinterpret_cast<const bfrag*>(
                    sB + rb * 64 + ((kk * 32 + (lane >> 4) * 8) ^ ((rb & 7) * 8)));
            }
#pragma unroll
            for (int fm = 0; fm < 4; ++fm)
#pragma unroll
                for (int fn = 0; fn < 4; ++fn)
                    acc[fm][fn] =
                        __builtin_amdgcn_mfma_f32_16x16x32_bf16(a[fm], b[fn], acc[fm][fn], 0, 0, 0);
        }
        __syncthreads();
    }

    // epilogue: C/D layout col=lane&15, row=(lane>>4)*4+r  [m89-verified]
    if constexpr (EPI == 1) {
#pragma unroll
        for (int fm = 0; fm < 4; ++fm)
#pragma unroll
            for (int fn = 0; fn < 4; ++fn) {
                int sbase = m0 + wr * 64 + fm * 16 + ((lane >> 4) << 2);
                int gcol = n0 + wc * 64 + fn * 16 + (lane & 15);
                int b = sbase >> 11, s = sbase & 2047, h = gcol >> 6, d = gcol & 63;
                ushort4 o;
                o.x = f2bf(acc[fm][fn][0]); o.y = f2bf(acc[fm][fn][1]);
                o.z = f2bf(acc[fm][fn][2]); o.w = f2bf(acc[fm][fn][3]);
                *reinterpret_cast<ushort4*>((unsigned short*)Out +
                                            ((size_t)(b * NH + h) * DH + d) * S_LEN + s) = o;
            }
    } else {
#pragma unroll
        for (int fm = 0; fm < 4; ++fm)
#pragma unroll
            for (int fn = 0; fn < 4; ++fn)
#pragma unroll
                for (int r = 0; r < 4; ++r) {
                    int grow = m0 + wr * 64 + fm * 16 + ((lane >> 4) << 2) + r;
                    int gcol = n0 + wc * 64 + fn * 16 + (lane & 15);
                    float v = acc[fm][fn][r];
                    if constexpr (EPI == 0) {
                        int b = grow >> 11, s = grow & 2047, h = gcol >> 6, d = gcol & 63;
                        ((unsigned short*)Out)[((size_t)(b * NH + h) * S_LEN + s) * DH + d] =
                            f2bf(v);
                    } else {
                        ((float*)Out)[(size_t)grow * N + gcol] = v;
                    }
                }
    }
}

// ---------------- scores = q @ k^T * scale + prev ----------------
__global__ __launch_bounds__(256) void scores_kernel(const unsigned short* __restrict__ qh,
                                                     const unsigned short* __restrict__ kh,
                                                     const float* __restrict__ prev,
                                                     float* __restrict__ scores) {
    const int z = blockIdx.z;  // b*NH + h
    const int tid = threadIdx.x;
    const int lane = tid & 63;
    const int w = tid >> 6, wr = w >> 1, wc = w & 1;
    const int m0 = blockIdx.y * 128, n0 = blockIdx.x * 128;
    const unsigned short* A = qh + (size_t)z * S_LEN * DH;
    const unsigned short* Bt = kh + (size_t)z * S_LEN * DH;

    __shared__ unsigned short sA[128 * 64];
    __shared__ unsigned short sB[128 * 64];

#pragma unroll
    for (int i = 0; i < 4; ++i) {
        int c = i * 256 + tid;
        int row = c >> 3, col8 = c & 7;
        int swz = (col8 * 8) ^ ((row & 7) * 8);
        *reinterpret_cast<int4*>(sA + row * 64 + swz) =
            *reinterpret_cast<const int4*>(A + (size_t)(m0 + row) * DH + col8 * 8);
        *reinterpret_cast<int4*>(sB + row * 64 + swz) =
            *reinterpret_cast<const int4*>(Bt + (size_t)(n0 + row) * DH + col8 * 8);
    }
    __syncthreads();

    f32x4 acc[4][4];
#pragma unroll
    for (int i = 0; i < 4; ++i)
#pragma unroll
        for (int j = 0; j < 4; ++j) acc[i][j] = (f32x4){0.f, 0.f, 0.f, 0.f};

#pragma unroll
    for (int kk = 0; kk < 2; ++kk) {
        bfrag a[4], b[4];
#pragma unroll
        for (int f = 0; f < 4; ++f) {
            int ra = wr * 64 + f * 16 + (lane & 15);
            a[f] = *reinterpret_cast<const bfrag*>(
                sA + ra * 64 + ((kk * 32 + (lane >> 4) * 8) ^ ((ra & 7) * 8)));
            int rb = wc * 64 + f * 16 + (lane & 15);
            b[f] = *reinterpret_cast<const bfrag*>(
                sB + rb * 64 + ((kk * 32 + (lane >> 4) * 8) ^ ((rb & 7) * 8)));
        }
#pragma unroll
        for (int fm = 0; fm < 4; ++fm)
#pragma unroll
            for (int fn = 0; fn < 4; ++fn)
                acc[fm][fn] =
                    __builtin_amdgcn_mfma_f32_16x16x32_bf16(a[fm], b[fn], acc[fm][fn], 0, 0, 0);
    }

    const float scale = 0.125f;  // 1/sqrt(64)
#pragma unroll
    for (int fm = 0; fm < 4; ++fm)
#pragma unroll
        for (int fn = 0; fn < 4; ++fn)
#pragma unroll
            for (int r = 0; r < 4; ++r) {
                int grow = m0 + wr * 64 + fm * 16 + ((lane >> 4) << 2) + r;
                int gcol = n0 + wc * 64 + fn * 16 + (lane & 15);
                size_t idx = (size_t)z * S_LEN * S_LEN + (size_t)grow * S_LEN + gcol;
                scores[idx] = acc[fm][fn][r] * scale + prev[idx];
            }
}

// ---------------- row softmax: one wave per row of 2048 ----------------
__global__ __launch_bounds__(256) void softmax_kernel(const float* __restrict__ scores,
                                                      float* __restrict__ attn) {
    const size_t row = (size_t)blockIdx.x * 4 + (threadIdx.x >> 6);
    const int lane = threadIdx.x & 63;
    const float* rp = scores + row * S_LEN;
    float4 v[8];
    float m = -1e30f;
#pragma unroll
    for (int it = 0; it < 8; ++it) {
        v[it] = *reinterpret_cast<const float4*>(rp + (it * 64 + lane) * 4);
        m = fmaxf(m, fmaxf(fmaxf(v[it].x, v[it].y), fmaxf(v[it].z, v[it].w)));
    }
#pragma unroll
    for (int s = 32; s >= 1; s >>= 1) m = fmaxf(m, __shfl_xor(m, s));
    float sum = 0.f;
#pragma unroll
    for (int it = 0; it < 8; ++it) {
        v[it].x = __expf(v[it].x - m); v[it].y = __expf(v[it].y - m);
        v[it].z = __expf(v[it].z - m); v[it].w = __expf(v[it].w - m);
        sum += v[it].x + v[it].y + v[it].z + v[it].w;
    }
#pragma unroll
    for (int s = 32; s >= 1; s >>= 1) sum += __shfl_xor(sum, s);
    const float inv = 1.0f / sum;
    float* op = attn + row * S_LEN;
#pragma unroll
    for (int it = 0; it < 8; ++it) {
        float4 o = make_float4(v[it].x * inv, v[it].y * inv, v[it].z * inv, v[it].w * inv);
        *reinterpret_cast<float4*>(op + (it * 64 + lane) * 4) = o;
    }
}

// ---------------- context = attn @ v  (per b,h) ----------------
// A: attn fp32 [S][S] (cast to bf16 during staging), Bt: vT bf16 [DH][S].
// M=2048, N=64, K=2048. Tile 128x64, BK=64, 4 waves (2x2), wave=64x32.
__global__ __launch_bounds__(256) void pv_kernel(const float* __restrict__ attn,
                                                 const unsigned short* __restrict__ vT,
                                                 unsigned short* __restrict__ ctx) {
    const int z = blockIdx.z;
    const int tid = threadIdx.x, lane = tid & 63;
    const int w = tid >> 6, wr = w >> 1, wc = w & 1;
    const int m0 = blockIdx.x * 128;
    const float* Az = attn + (size_t)z * S_LEN * S_LEN;
    const unsigned short* Bz = vT + (size_t)z * DH * S_LEN;

    __shared__ unsigned short sA[128 * 64];
    __shared__ unsigned short sB[64 * 64];

    f32x4 acc[4][2];
#pragma unroll
    for (int i = 0; i < 4; ++i)
#pragma unroll
        for (int j = 0; j < 2; ++j) acc[i][j] = (f32x4){0.f, 0.f, 0.f, 0.f};

    for (int k0 = 0; k0 < S_LEN; k0 += 64) {
#pragma unroll
        for (int i = 0; i < 8; ++i) {
            int c = i * 256 + tid;  // 2048 chunks of 4 fp32
            int row = c >> 4, col4 = c & 15;
            float4 v = *reinterpret_cast<const float4*>(Az + (size_t)(m0 + row) * S_LEN + k0 +
                                                        col4 * 4);
            ushort4 o;
            o.x = f2bf(v.x); o.y = f2bf(v.y); o.z = f2bf(v.z); o.w = f2bf(v.w);
            *reinterpret_cast<ushort4*>(sA + row * 64 + ((col4 * 4) ^ ((row & 7) * 8))) = o;
        }
#pragma unroll
        for (int i = 0; i < 2; ++i) {
            int c = i * 256 + tid;  // 512 chunks of 8 bf16
            int row = c >> 3, col8 = c & 7;
            *reinterpret_cast<int4*>(sB + row * 64 + ((col8 * 8) ^ ((row & 7) * 8))) =
                *reinterpret_cast<const int4*>(Bz + (size_t)row * S_LEN + k0 + col8 * 8);
        }
        __syncthreads();
#pragma unroll
        for (int kk = 0; kk < 2; ++kk) {
            bfrag a[4], b[2];
#pragma unroll
            for (int f = 0; f < 4; ++f) {
                int ra = wr * 64 + f * 16 + (lane & 15);
                a[f] = *reinterpret_cast<const bfrag*>(
                    sA + ra * 64 + ((kk * 32 + (lane >> 4) * 8) ^ ((ra & 7) * 8)));
            }
#pragma unroll
            for (int f = 0; f < 2; ++f) {
                int rb = wc * 32 + f * 16 + (lane & 15);
                b[f] = *reinterpret_cast<const bfrag*>(
                    sB + rb * 64 + ((kk * 32 + (lane >> 4) * 8) ^ ((rb & 7) * 8)));
            }
#pragma unroll
            for (int fm = 0; fm < 4; ++fm)
#pragma unroll
                for (int fn = 0; fn < 2; ++fn)
                    acc[fm][fn] =
                        __builtin_amdgcn_mfma_f32_16x16x32_bf16(a[fm], b[fn], acc[fm][fn], 0, 0, 0);
        }
        __syncthreads();
    }

    const int b = z >> 4, h = z & 15;
#pragma unroll
    for (int fm = 0; fm < 4; ++fm)
#pragma unroll
        for (int fn = 0; fn < 2; ++fn)
#pragma unroll
            for (int r = 0; r < 4; ++r) {
                int s = m0 + wr * 64 + fm * 16 + ((lane >> 4) << 2) + r;
                int d = wc * 32 + fn * 16 + (lane & 15);
                ctx[((size_t)(b * S_LEN + s)) * DM + h * DH + d] = f2bf(acc[fm][fn][r]);
            }
}

extern "C" void kernel_launch(void* const* d_in, const int* in_sizes, int n_in, void* d_out,
                              int out_size, void* d_ws, size_t ws_size, hipStream_t stream) {
    const float* Q = (const float*)d_in[0];
    const float* K = (const float*)d_in[1];
    const float* V = (const float*)d_in[2];
    const float* prev = (const float*)d_in[3];
    const float* Wq = (const float*)d_in[4];
    const float* Wk = (const float*)d_in[5];
    const float* Wv = (const float*)d_in[6];
    const float* Wo = (const float*)d_in[7];

    float* out = (float*)d_out;
    float* attn = out + (size_t)BS * DM;
    float* scores = attn + (size_t)NB * NH * S_LEN * S_LEN;

    unsigned short* ws = (unsigned short*)d_ws;
    unsigned short* Qc = ws;
    unsigned short* Kc = Qc + (size_t)BS * DM;
    unsigned short* Vc = Kc + (size_t)BS * DM;
    unsigned short* Wqc = Vc + (size_t)BS * DM;
    unsigned short* Wkc = Wqc + (size_t)DM * DM;
    unsigned short* Wvc = Wkc + (size_t)DM * DM;
    unsigned short* Woc = Wvc + (size_t)DM * DM;
    unsigned short* qh = Woc + (size_t)DM * DM;   // (b,h,s,d) bf16
    unsigned short* kh = qh + (size_t)BS * DM;    // (b,h,s,d) bf16
    unsigned short* vT = kh + (size_t)BS * DM;    // (b,h,d,s) bf16
    unsigned short* ctx = vT + (size_t)BS * DM;   // (b,s,h*d) bf16

    // casts
    cast_kernel<<<BS * DM / 4 / 256, 256, 0, stream>>>(Q, Qc, BS * DM / 4);
    cast_kernel<<<BS * DM / 4 / 256, 256, 0, stream>>>(K, Kc, BS * DM / 4);
    cast_kernel<<<BS * DM / 4 / 256, 256, 0, stream>>>(V, Vc, BS * DM / 4);
    cast_kernel<<<DM * DM / 4 / 256, 256, 0, stream>>>(Wq, Wqc, DM * DM / 4);
    cast_kernel<<<DM * DM / 4 / 256, 256, 0, stream>>>(Wk, Wkc, DM * DM / 4);
    cast_kernel<<<DM * DM / 4 / 256, 256, 0, stream>>>(Wv, Wvc, DM * DM / 4);
    cast_kernel<<<DM * DM / 4 / 256, 256, 0, stream>>>(Wo, Woc, DM * DM / 4);

    // projections
    dim3 gp(DM / 128, BS / 128, 1);
    gemm_bt<0><<<gp, 256, 0, stream>>>(Qc, Wqc, qh, BS, DM, DM);
    gemm_bt<0><<<gp, 256, 0, stream>>>(Kc, Wkc, kh, BS, DM, DM);
    gemm_bt<1><<<gp, 256, 0, stream>>>(Vc, Wvc, vT, BS, DM, DM);

    // scores = q k^T * scale + prev
    dim3 gs(S_LEN / 128, S_LEN / 128, NB * NH);
    scores_kernel<<<gs, 256, 0, stream>>>(qh, kh, prev, scores);

    // softmax -> attn
    softmax_kernel<<<NB * NH * S_LEN / 4, 256, 0, stream>>>(scores, attn);

    // context = attn @ v
    dim3 gv(S_LEN / 128, 1, NB * NH);
    pv_kernel<<<gv, 256, 0, stream>>>(attn, vT, ctx);

    // output projection
    gemm_bt<2><<<gp, 256, 0, stream>>>(ctx, Woc, out, BS, DM, DM);
}